// Round 14
// baseline (256.522 us; speedup 1.0000x reference)
//
#include <hip/hip_runtime.h>
#include <hip/hip_bf16.h>
#include <hip/hip_fp16.h>
#include <stdint.h>

#define HH 80
#define WW 80
#define LL 6400
#define CC 32
#define BB 2
#define COG 16
#define DELTA 0.011f
#define NT8 800

typedef __bf16 bf16x8 __attribute__((ext_vector_type(8)));
typedef float  f32x4  __attribute__((ext_vector_type(4)));

__device__ __forceinline__ int div80(int v) {
    return (int)(((unsigned)v * 52429u) >> 22);   // exact for 0 <= v < 52428
}

__device__ __forceinline__ unsigned short f2bf(float f) {
    unsigned int u = __float_as_uint(f);
    return (unsigned short)((u + 0x7fffu + ((u >> 16) & 1u)) >> 16);   // RNE
}

__device__ __forceinline__ void gload_lds16(const void* g, void* l) {
    __builtin_amdgcn_global_load_lds(
        (const __attribute__((address_space(1))) void*)g,
        (__attribute__((address_space(3))) void*)l, 16, 0, 0);
}

// ---------------- fusedunf: per (b,mat,row y): image->LDS, norms, unf fp32, bf16 packs ----------------
__global__ __launch_bounds__(256) void fusedunf_kernel(const float* __restrict__ HSI,
                                                       const float* __restrict__ PAN,
                                                       float* __restrict__ invH,
                                                       float* __restrict__ invP,
                                                       float* __restrict__ PANunf,
                                                       float* __restrict__ HSIunf,
                                                       char* __restrict__ Apack,
                                                       char* __restrict__ Bpack) {
    __shared__ float simg[CC][3][82];   // [c][dy][x+1], 31.5 KB
    __shared__ float sinv[80];
    const int y = blockIdx.x, mat = blockIdx.y, b = blockIdx.z;
    const int tid = threadIdx.x;
    const float* img = (mat ? HSI : PAN) + (size_t)b * CC * LL;

    for (int i = tid; i < CC * 3; i += 256) {
        simg[i / 3][i % 3][0] = 0.f;
        simg[i / 3][i % 3][81] = 0.f;
    }
    for (int i = tid; i < CC * 3 * 80; i += 256) {
        int c = i / 240, r = i - c * 240;
        int dy = r / 80, x = r - dy * 80;
        int yy = y + dy - 1;
        float v = ((unsigned)yy < 80u) ? img[(size_t)c * LL + yy * 80 + x] : 0.f;
        simg[c][dy][x + 1] = v;
    }
    __syncthreads();

    if (tid < 80) {
        float s = 0.f;
        #pragma unroll 4
        for (int c = 0; c < CC; ++c)
            #pragma unroll
            for (int dy = 0; dy < 3; ++dy)
                #pragma unroll
                for (int dx = 0; dx < 3; ++dx) {
                    float v = simg[c][dy][tid + dx];
                    s = fmaf(v, v, s);
                }
        float inv = 1.f / fmaxf(sqrtf(s), 1e-12f);
        sinv[tid] = inv;
        (mat ? invH : invP)[b * LL + y * 80 + tid] = inv;
    }
    __syncthreads();

    // unf fp32 write (l-major, raw) — consumed by scanfix
    {
        float* unfBase = (mat ? HSIunf : PANunf) + ((size_t)b * LL + y * 80) * 288;
        for (int i = tid; i < 5760; i += 256) {
            const int fidx = i * 4;
            const int l = fidx / 288, k = fidx - l * 288;
            float4 v;
            {
                int kk = k;     int c = kk / 9, t = kk - c * 9; v.x = simg[c][t / 3][l + t % 3];
                kk = k + 1;     c = kk / 9; t = kk - c * 9;     v.y = simg[c][t / 3][l + t % 3];
                kk = k + 2;     c = kk / 9; t = kk - c * 9;     v.z = simg[c][t / 3][l + t % 3];
                kk = k + 3;     c = kk / 9; t = kk - c * 9;     v.w = simg[c][t / 3][l + t % 3];
            }
            *(float4*)(unfBase + fidx) = v;
        }
    }

    // row-interleaved bf16 pack write (both operands), same bytes as the 221us run
    {
        char* pk = mat ? Bpack : Apack;
        for (int i = tid; i < 2880; i += 256) {
            const int l = i / 36, g = i - l * 36;
            const float inv = sinv[l];
            unsigned short hs[8];
            #pragma unroll
            for (int jj = 0; jj < 8; ++jj) {
                int kk = g * 8 + jj;
                int c = kk / 9, t = kk - c * 9;
                hs[jj] = f2bf(simg[c][t / 3][l + t % 3] * inv);
            }
            const int q = g / 12;
            const int slot = (g % 12) ^ (l & 15);
            size_t off = ((size_t)(b * 3 + q) * LL + y * 80 + l) * 256 + slot * 16;
            uint4 hv;
            hv.x = hs[0] | ((unsigned)hs[1] << 16); hv.y = hs[2] | ((unsigned)hs[3] << 16);
            hv.z = hs[4] | ((unsigned)hs[5] << 16); hv.w = hs[6] | ((unsigned)hs[7] << 16);
            *(uint4*)(pk + off) = hv;
        }
    }
}

// ---------------- simq: A LDS-dbuf + counted vmcnt, hoisted B frags (221us-run structure) -----------
// Adds tileMax64 emission (wave-level max; bit-consistent with tileMax8 under RNE monotonicity).
__global__ __launch_bounds__(256, 2) void simq_kernel(const char* __restrict__ Apack,
                                                      const char* __restrict__ Bpack,
                                                      __half* __restrict__ tileMax8,
                                                      __half* __restrict__ tileMax64) {
    __shared__ __align__(16) char Alds[2][32768];
    // bijective XCD swizzle for nwg=500: q=62, r=4
    const int orig = blockIdx.x;
    const int xcd = orig & 7, idx = orig >> 3;
    const int wg = (xcd < 4 ? xcd * 63 : 252 + (xcd - 4) * 62) + idx;
    const int b = wg / 250;
    int rest = wg - b * 250;
    const int sp = rest / 50;
    const int mt = rest - sp * 50;

    const int tid = threadIdx.x;
    const int lane = tid & 63, w = tid >> 6;
    const int wl = w >> 1, wm = w & 1;
    const int r15 = lane & 15, h = lane >> 4;
    const char* Ab = Apack + (size_t)b * 3 * LL * 256;
    const char* Bb = Bpack + (size_t)b * 3 * LL * 256;
    const int m0 = mt * 128;
    const f32x4 fzero = {0.f, 0.f, 0.f, 0.f};

    // B fragments: load once (hoisted); reloads hit L1/L2
    bf16x8 bq[3][3][4];
    {
        const int rowb = m0 + wm * 64 + r15;
        #pragma unroll
        for (int c = 0; c < 3; ++c)
            #pragma unroll
            for (int ks = 0; ks < 3; ++ks)
                #pragma unroll
                for (int fm = 0; fm < 4; ++fm) {
                    const int gp = ((ks * 4 + h) ^ r15) * 16;
                    bq[c][ks][fm] = *(const bf16x8*)(Bb + ((size_t)c * LL + rowb + fm * 16) * 256 + gp);
                }
    }

    const char* gAbase = Ab + w * 8192 + lane * 16;
    char* lA0 = Alds[0] + w * 8192;
    char* lA1 = Alds[1] + w * 8192;

    // prologue: stage A (lt=0, c=0) into buf 0
    {
        const char* gA = gAbase + ((size_t)(sp * 10) * 128) * 256;
        #pragma unroll
        for (int i = 0; i < 8; ++i) gload_lds16(gA + i * 1024, lA0 + i * 1024);
    }

    int cur = 0;
    #pragma unroll 1
    for (int lt = 0; lt < 10; ++lt) {
        const int l0 = (sp * 10 + lt) * 128;
        f32x4 acc[4][4];
        #pragma unroll
        for (int i = 0; i < 4; ++i)
            #pragma unroll
            for (int j = 0; j < 4; ++j) acc[i][j] = fzero;

        #pragma unroll
        for (int c = 0; c < 3; ++c) {
            if (c < 2 || lt < 9) {
                const int c2  = (c + 1) % 3;
                const int l0n = (c == 2) ? l0 + 128 : l0;
                const char* gA = gAbase + ((size_t)c2 * LL + l0n) * 256;
                char* lA = (cur ^ 1) ? lA1 : lA0;
                #pragma unroll
                for (int i = 0; i < 8; ++i) gload_lds16(gA + i * 1024, lA + i * 1024);
                asm volatile("s_waitcnt vmcnt(8)" ::: "memory");
            } else {
                asm volatile("s_waitcnt vmcnt(0)" ::: "memory");
            }
            __builtin_amdgcn_s_barrier();
            asm volatile("" ::: "memory");
            const char* lAr = Alds[cur];
            #pragma unroll
            for (int ks = 0; ks < 3; ++ks) {
                const int gp = ((ks * 4 + h) ^ r15) * 16;
                bf16x8 af[4];
                #pragma unroll
                for (int f = 0; f < 4; ++f)
                    af[f] = *(const bf16x8*)(lAr + (wl * 64 + f * 16 + r15) * 256 + gp);
                #pragma unroll
                for (int fl = 0; fl < 4; ++fl)
                    #pragma unroll
                    for (int fm = 0; fm < 4; ++fm)
                        acc[fl][fm] = __builtin_amdgcn_mfma_f32_16x16x32_bf16(
                            af[fl], bq[c][ks][fm], acc[fl][fm], 0, 0, 0);
            }
            asm volatile("s_waitcnt lgkmcnt(0)" ::: "memory");
            __builtin_amdgcn_s_barrier();
            asm volatile("" ::: "memory");
            cur ^= 1;
        }

        // fold: 8-row subtile maxes + 64-row wave max (tm64 == max(tm8); RNE monotone)
        const int T64 = (sp * 10 + lt) * 2 + wl;
        #pragma unroll
        for (int fm = 0; fm < 4; ++fm) {
            float m4[4];
            #pragma unroll
            for (int fl = 0; fl < 4; ++fl) {
                f32x4 a = acc[fl][fm];
                m4[fl] = fmaxf(fmaxf(a[0], a[1]), fmaxf(a[2], a[3]));
            }
            const int m = m0 + wm * 64 + fm * 16 + r15;
            #pragma unroll
            for (int fl = 0; fl < 4; ++fl) {
                float v = fmaxf(m4[fl], __shfl_xor(m4[fl], 16, 64));
                if ((h & 1) == 0)
                    tileMax8[((size_t)b * LL + m) * NT8 + T64 * 8 + fl * 2 + (h >> 1)] = __float2half(v);
            }
            float vA = fmaxf(fmaxf(m4[0], m4[1]), fmaxf(m4[2], m4[3]));
            vA = fmaxf(vA, __shfl_xor(vA, 16, 64));
            vA = fmaxf(vA, __shfl_xor(vA, 32, 64));
            if (h == 0)
                tileMax64[((size_t)b * LL + m) * 100 + T64] = __float2half(vA);
        }
    }
}

// ---------------- scanfix: 2-level scan (tm64 -> tm8) + exact fp32 rescore ----------------
__global__ __launch_bounds__(256) void scanfix_kernel(const float* __restrict__ PANunf,
                                                      const float* __restrict__ HSIunf,
                                                      const float* __restrict__ invH,
                                                      const float* __restrict__ invP,
                                                      const __half* __restrict__ tileMax8,
                                                      const __half* __restrict__ tileMax64,
                                                      float* __restrict__ Sv, int* __restrict__ Sa) {
    // bijective XCD swizzle (3200 % 8 == 0)
    const int orig = blockIdx.x;
    const int swz = (orig & 7) * 400 + (orig >> 3);
    const int gw = swz * 4 + (threadIdx.x >> 6);   // b*LL + m
    const int lane = threadIdx.x & 63;
    const int b = gw / LL;
    const __half* tm64 = tileMax64 + (size_t)gw * 100;
    const __half* tm8  = tileMax8  + (size_t)gw * NT8;

    float t64[2];
    #pragma unroll
    for (int i = 0; i < 2; ++i) {
        int T = i * 64 + lane;
        t64[i] = (T < 100) ? __half2float(tm64[T]) : -3.0e38f;
    }
    float v1 = fmaxf(t64[0], t64[1]);
    #pragma unroll
    for (int d = 1; d < 64; d <<= 1) v1 = fmaxf(v1, __shfl_xor(v1, d, 64));
    const float th = v1 - DELTA;

    const float ihm = invH[gw];
    const int lql = lane >> 3, kq = lane & 7;

    float hreg[36];
    {
        const float4* hv4 = (const float4*)(HSIunf + (size_t)gw * 288 + kq * 36);
        #pragma unroll
        for (int j = 0; j < 9; ++j) {
            float4 v = hv4[j];
            hreg[j * 4 + 0] = v.x; hreg[j * 4 + 1] = v.y;
            hreg[j * 4 + 2] = v.z; hreg[j * 4 + 3] = v.w;
        }
    }

    float bv = -3.0e38f; int bl = 0x7fffffff;

    #pragma unroll 1
    for (int i = 0; i < 2; ++i) {
        unsigned long long mask = __ballot(t64[i] >= th);
        while (mask) {
            const int t = __ffsll((long long)mask) - 1;
            mask &= mask - 1;
            const int T64 = i * 64 + t;
            // descend: candidate set identical to flat scan since tm64 == max(tm8)
            float s8 = __half2float(tm8[T64 * 8 + (lane & 7)]);
            unsigned sub = (unsigned)(__ballot(s8 >= th) & 0xffull);
            while (sub) {
                const int j = __ffs(sub) - 1;
                sub &= sub - 1;
                const int T = T64 * 8 + j;
                const int l = T * 8 + lql;
                const float4* pv4 = (const float4*)(PANunf + ((size_t)b * LL + l) * 288 + kq * 36);
                float part = 0.f;
                #pragma unroll
                for (int jj = 0; jj < 9; ++jj) {
                    float4 p = pv4[jj];
                    part = fmaf(p.x, hreg[jj * 4 + 0], part);
                    part = fmaf(p.y, hreg[jj * 4 + 1], part);
                    part = fmaf(p.z, hreg[jj * 4 + 2], part);
                    part = fmaf(p.w, hreg[jj * 4 + 3], part);
                }
                part += __shfl_xor(part, 1, 64);
                part += __shfl_xor(part, 2, 64);
                part += __shfl_xor(part, 4, 64);
                const float val = part * invP[b * LL + l] * ihm;
                if (val > bv || (val == bv && l < bl)) { bv = val; bl = l; }
            }
        }
    }
    #pragma unroll
    for (int d = 1; d < 64; d <<= 1) {
        float ov = __shfl_xor(bv, d, 64);
        int   ol = __shfl_xor(bl, d, 64);
        if (ov > bv || (ov == bv && ol < bl)) { bv = ov; bl = ol; }
    }
    if (lane == 0) { Sv[gw] = bv; Sa[gw] = bl; }
}

// ---------------- T_lv3 = fold3x3(gathered PAN patches) / 9 ----------------
__global__ void tfold_kernel(const float* __restrict__ PAN, const int* __restrict__ Sa,
                             float* __restrict__ T) {
    int g = blockIdx.x * blockDim.x + threadIdx.x;
    if (g >= BB * CC * LL) return;
    int bc = g / LL, l = g - bc * LL;
    int b = bc >> 5;
    int y = div80(l), x = l - y * 80;
    const float* img = PAN + (size_t)bc * LL;
    const int* Sab = Sa + b * LL;
    float acc = 0.f;
    #pragma unroll
    for (int i = 0; i < 3; ++i) {
        int yp = y + 1 - i;
        if ((unsigned)yp >= 80u) continue;
        #pragma unroll
        for (int j = 0; j < 3; ++j) {
            int xp = x + 1 - j;
            if ((unsigned)xp >= 80u) continue;
            int a = Sab[yp * 80 + xp];
            int ya = div80(a), xa = a - ya * 80;
            int py = ya + i - 1, px = xa + j - 1;
            if ((unsigned)py < 80u && (unsigned)px < 80u) acc += img[py * 80 + px];
        }
    }
    T[g] = acc * (1.f / 9.f);
}

// ---------------- conv1: h = relu(conv3x3(concat(T,HSI), w1) + b1) ----------------
__global__ __launch_bounds__(256) void conv1_kernel(const float* __restrict__ T,
                                                    const float* __restrict__ HSI,
                                                    const float* __restrict__ w1,
                                                    const float* __restrict__ b1,
                                                    float* __restrict__ h) {
    __shared__ __align__(16) float wl[64][9][COG];   // 36.9 KB
    const int tid = threadIdx.x;
    const int co0 = blockIdx.y * COG;
    for (int idx = tid; idx < 64 * 9 * COG; idx += 256) {
        int cog = idx & (COG - 1);
        int rest = idx >> 4;
        int cin = rest / 9, tap = rest - cin * 9;
        wl[cin][tap][cog] = w1[(co0 + cog) * (64 * 9) + cin * 9 + tap];
    }
    __syncthreads();
    const int g = blockIdx.x * 256 + tid;
    const int b = g / LL, l = g - b * LL;
    const int y = div80(l), x = l - y * 80;
    float acc[COG];
    #pragma unroll
    for (int i = 0; i < COG; ++i) acc[i] = 0.f;
    for (int cin = 0; cin < 64; ++cin) {
        const float* img = (cin < CC) ? (T + (size_t)(b * CC + cin) * LL)
                                      : (HSI + (size_t)(b * CC + (cin - CC)) * LL);
        float tap[9];
        #pragma unroll
        for (int i = 0; i < 3; ++i)
            #pragma unroll
            for (int j = 0; j < 3; ++j) {
                int yy = y + i - 1, xx = x + j - 1;
                tap[i * 3 + j] = ((unsigned)yy < 80u && (unsigned)xx < 80u) ? img[yy * 80 + xx] : 0.f;
            }
        #pragma unroll
        for (int t9 = 0; t9 < 9; ++t9) {
            #pragma unroll
            for (int q4 = 0; q4 < COG / 4; ++q4) {
                const float4 wv = *reinterpret_cast<const float4*>(&wl[cin][t9][q4 * 4]);
                acc[q4 * 4 + 0] = fmaf(tap[t9], wv.x, acc[q4 * 4 + 0]);
                acc[q4 * 4 + 1] = fmaf(tap[t9], wv.y, acc[q4 * 4 + 1]);
                acc[q4 * 4 + 2] = fmaf(tap[t9], wv.z, acc[q4 * 4 + 2]);
                acc[q4 * 4 + 3] = fmaf(tap[t9], wv.w, acc[q4 * 4 + 3]);
            }
        }
    }
    #pragma unroll
    for (int cog = 0; cog < COG; ++cog) {
        float v = acc[cog] + b1[co0 + cog];
        h[(size_t)(b * CC + co0 + cog) * LL + l] = fmaxf(v, 0.f);
    }
}

// ---------------- conv2: out = (conv3x3(h, w2) + b2) * S + HSI ----------------
__global__ __launch_bounds__(256) void conv2_kernel(const float* __restrict__ hbuf,
                                                    const float* __restrict__ HSI,
                                                    const float* __restrict__ Sv,
                                                    const float* __restrict__ w2,
                                                    const float* __restrict__ b2,
                                                    float* __restrict__ out) {
    __shared__ __align__(16) float wl[CC][9][COG];   // 18.4 KB
    const int tid = threadIdx.x;
    const int co0 = blockIdx.y * COG;
    for (int idx = tid; idx < CC * 9 * COG; idx += 256) {
        int cog = idx & (COG - 1);
        int rest = idx >> 4;
        int cin = rest / 9, tap = rest - cin * 9;
        wl[cin][tap][cog] = w2[(co0 + cog) * (CC * 9) + cin * 9 + tap];
    }
    __syncthreads();
    const int g = blockIdx.x * 256 + tid;
    const int b = g / LL, l = g - b * LL;
    const int y = div80(l), x = l - y * 80;
    float acc[COG];
    #pragma unroll
    for (int i = 0; i < COG; ++i) acc[i] = 0.f;
    for (int cin = 0; cin < CC; ++cin) {
        const float* img = hbuf + (size_t)(b * CC + cin) * LL;
        float tap[9];
        #pragma unroll
        for (int i = 0; i < 3; ++i)
            #pragma unroll
            for (int j = 0; j < 3; ++j) {
                int yy = y + i - 1, xx = x + j - 1;
                tap[i * 3 + j] = ((unsigned)yy < 80u && (unsigned)xx < 80u) ? img[yy * 80 + xx] : 0.f;
            }
        #pragma unroll
        for (int t9 = 0; t9 < 9; ++t9) {
            #pragma unroll
            for (int q4 = 0; q4 < COG / 4; ++q4) {
                const float4 wv = *reinterpret_cast<const float4*>(&wl[cin][t9][q4 * 4]);
                acc[q4 * 4 + 0] = fmaf(tap[t9], wv.x, acc[q4 * 4 + 0]);
                acc[q4 * 4 + 1] = fmaf(tap[t9], wv.y, acc[q4 * 4 + 1]);
                acc[q4 * 4 + 2] = fmaf(tap[t9], wv.z, acc[q4 * 4 + 2]);
                acc[q4 * 4 + 3] = fmaf(tap[t9], wv.w, acc[q4 * 4 + 3]);
            }
        }
    }
    const float s = Sv[b * LL + l];
    #pragma unroll
    for (int cog = 0; cog < COG; ++cog) {
        int c = co0 + cog;
        out[(size_t)(b * CC + c) * LL + l] = fmaf(acc[cog] + b2[c], s, HSI[(size_t)(b * CC + c) * LL + l]);
    }
}

extern "C" void kernel_launch(void* const* d_in, const int* in_sizes, int n_in,
                              void* d_out, int out_size, void* d_ws, size_t ws_size,
                              hipStream_t stream) {
    const float* HSI = (const float*)d_in[0];
    const float* PAN = (const float*)d_in[1];
    const float* w1  = (const float*)d_in[2];
    const float* b1  = (const float*)d_in[3];
    const float* w2  = (const float*)d_in[4];
    const float* b2  = (const float*)d_in[5];
    float* out = (float*)d_out;

    char* ws = (char*)d_ws;
    size_t off = 0;
    auto alloc = [&](size_t bytes) -> void* {
        void* p = ws + off;
        off += (bytes + 255) & ~(size_t)255;
        return p;
    };
    float* invH  = (float*)alloc((size_t)BB * LL * 4);
    float* invP  = (float*)alloc((size_t)BB * LL * 4);
    char*  Apack = (char*) alloc((size_t)BB * 3 * LL * 256);   // 9.83 MB
    char*  Bpack = (char*) alloc((size_t)BB * 3 * LL * 256);   // 9.83 MB
    __half* tileMax8  = (__half*)alloc((size_t)BB * LL * NT8 * 2);  // 20.5 MB
    __half* tileMax64 = (__half*)alloc((size_t)BB * LL * 100 * 2);  // 2.56 MB
    float* PANunf = (float*)alloc((size_t)BB * LL * 288 * 4);  // 14.75 MB
    float* HSIunf = (float*)alloc((size_t)BB * LL * 288 * 4);  // 14.75 MB
    float* Sv    = (float*)alloc((size_t)BB * LL * 4);
    int*   Sa    = (int*)  alloc((size_t)BB * LL * 4);
    float* T     = (float*)alloc((size_t)BB * CC * LL * 4);
    float* hbuf  = (float*)alloc((size_t)BB * CC * LL * 4);

    fusedunf_kernel<<<dim3(80, 2, BB), 256, 0, stream>>>(HSI, PAN, invH, invP,
                                                         PANunf, HSIunf, Apack, Bpack);
    simq_kernel<<<dim3(500), 256, 0, stream>>>(Apack, Bpack, tileMax8, tileMax64);
    scanfix_kernel<<<dim3(BB * LL / 4), 256, 0, stream>>>(PANunf, HSIunf, invH, invP,
                                                          tileMax8, tileMax64, Sv, Sa);
    tfold_kernel<<<dim3((BB * CC * LL + 255) / 256), 256, 0, stream>>>(PAN, Sa, T);
    conv1_kernel<<<dim3(BB * LL / 256, CC / COG), 256, 0, stream>>>(T, HSI, w1, b1, hbuf);
    conv2_kernel<<<dim3(BB * LL / 256, CC / COG), 256, 0, stream>>>(hbuf, HSI, Sv, w2, b2, out);
}

// Round 15
// 220.051 us; speedup vs baseline: 1.1657x; 1.1657x over previous
//
#include <hip/hip_runtime.h>
#include <hip/hip_bf16.h>
#include <hip/hip_fp16.h>
#include <stdint.h>

#define HH 80
#define WW 80
#define LL 6400
#define CC 32
#define BB 2
#define COG 16
#define DELTA 0.011f
#define NT8 800

typedef __bf16 bf16x8 __attribute__((ext_vector_type(8)));
typedef float  f32x4  __attribute__((ext_vector_type(4)));

__device__ __forceinline__ int div80(int v) {
    return (int)(((unsigned)v * 52429u) >> 22);   // exact for 0 <= v < 52428
}

__device__ __forceinline__ unsigned short f2bf(float f) {
    unsigned int u = __float_as_uint(f);
    return (unsigned short)((u + 0x7fffu + ((u >> 16) & 1u)) >> 16);   // RNE
}

__device__ __forceinline__ void gload_lds16(const void* g, void* l) {
    __builtin_amdgcn_global_load_lds(
        (const __attribute__((address_space(1))) void*)g,
        (__attribute__((address_space(3))) void*)l, 16, 0, 0);
}

// ---------------- fusedunf: per (b,mat,row y): image->LDS, norms, unf fp32, bf16 packs ----------------
__global__ __launch_bounds__(256) void fusedunf_kernel(const float* __restrict__ HSI,
                                                       const float* __restrict__ PAN,
                                                       float* __restrict__ invH,
                                                       float* __restrict__ invP,
                                                       float* __restrict__ PANunf,
                                                       float* __restrict__ HSIunf,
                                                       char* __restrict__ Apack,
                                                       char* __restrict__ Bpack) {
    __shared__ float simg[CC][3][82];   // [c][dy][x+1], 31.5 KB
    __shared__ float sinv[80];
    const int y = blockIdx.x, mat = blockIdx.y, b = blockIdx.z;
    const int tid = threadIdx.x;
    const float* img = (mat ? HSI : PAN) + (size_t)b * CC * LL;

    for (int i = tid; i < CC * 3; i += 256) {
        simg[i / 3][i % 3][0] = 0.f;
        simg[i / 3][i % 3][81] = 0.f;
    }
    for (int i = tid; i < CC * 3 * 80; i += 256) {
        int c = i / 240, r = i - c * 240;
        int dy = r / 80, x = r - dy * 80;
        int yy = y + dy - 1;
        float v = ((unsigned)yy < 80u) ? img[(size_t)c * LL + yy * 80 + x] : 0.f;
        simg[c][dy][x + 1] = v;
    }
    __syncthreads();

    if (tid < 80) {
        float s = 0.f;
        #pragma unroll 4
        for (int c = 0; c < CC; ++c)
            #pragma unroll
            for (int dy = 0; dy < 3; ++dy)
                #pragma unroll
                for (int dx = 0; dx < 3; ++dx) {
                    float v = simg[c][dy][tid + dx];
                    s = fmaf(v, v, s);
                }
        float inv = 1.f / fmaxf(sqrtf(s), 1e-12f);
        sinv[tid] = inv;
        (mat ? invH : invP)[b * LL + y * 80 + tid] = inv;
    }
    __syncthreads();

    // unf fp32 write: 80*288 floats = 5760 float4, consecutive threads -> consecutive 16B
    {
        float* unfBase = (mat ? HSIunf : PANunf) + ((size_t)b * LL + y * 80) * 288;
        for (int i = tid; i < 5760; i += 256) {
            const int fidx = i * 4;
            const int l = fidx / 288, k = fidx - l * 288;
            float4 v;
            {
                int kk = k;     int c = kk / 9, t = kk - c * 9; v.x = simg[c][t / 3][l + t % 3];
                kk = k + 1;     c = kk / 9; t = kk - c * 9;     v.y = simg[c][t / 3][l + t % 3];
                kk = k + 2;     c = kk / 9; t = kk - c * 9;     v.z = simg[c][t / 3][l + t % 3];
                kk = k + 3;     c = kk / 9; t = kk - c * 9;     v.w = simg[c][t / 3][l + t % 3];
            }
            *(float4*)(unfBase + fidx) = v;
        }
    }

    // bf16 pack write: 80*36 granules of 16B, row-interleaved swizzled layout
    {
        char* pk = mat ? Bpack : Apack;
        for (int i = tid; i < 2880; i += 256) {
            const int l = i / 36, g = i - l * 36;
            const float inv = sinv[l];
            unsigned short hs[8];
            #pragma unroll
            for (int jj = 0; jj < 8; ++jj) {
                int kk = g * 8 + jj;
                int c = kk / 9, t = kk - c * 9;
                hs[jj] = f2bf(simg[c][t / 3][l + t % 3] * inv);
            }
            const int q = g / 12;
            const int slot = (g % 12) ^ (l & 15);       // (y*80+l)&15 == l&15 since 80%16==0
            size_t off = ((size_t)(b * 3 + q) * LL + y * 80 + l) * 256 + slot * 16;
            uint4 hv;
            hv.x = hs[0] | ((unsigned)hs[1] << 16); hv.y = hs[2] | ((unsigned)hs[3] << 16);
            hv.z = hs[4] | ((unsigned)hs[5] << 16); hv.w = hs[6] | ((unsigned)hs[7] << 16);
            *(uint4*)(pk + off) = hv;
        }
    }
}

// ---------------- simq: MFMA similarity, B reg-resident, counted-vmcnt pipeline ----------------
__global__ __launch_bounds__(256, 2) void simq_kernel(const char* __restrict__ Apack,
                                                      const char* __restrict__ Bpack,
                                                      __half* __restrict__ tileMax8) {
    __shared__ __align__(16) char Alds[2][32768];
    // bijective XCD swizzle for nwg=500: q=62, r=4
    const int orig = blockIdx.x;
    const int xcd = orig & 7, idx = orig >> 3;
    const int wg = (xcd < 4 ? xcd * 63 : 252 + (xcd - 4) * 62) + idx;
    const int b = wg / 250;
    int rest = wg - b * 250;
    const int sp = rest / 50;
    const int mt = rest - sp * 50;

    const int tid = threadIdx.x;
    const int lane = tid & 63, w = tid >> 6;
    const int wl = w >> 1, wm = w & 1;
    const int r15 = lane & 15, h = lane >> 4;
    const char* Ab = Apack + (size_t)b * 3 * LL * 256;
    const char* Bb = Bpack + (size_t)b * 3 * LL * 256;
    const int m0 = mt * 128;
    const f32x4 fzero = {0.f, 0.f, 0.f, 0.f};

    // B fragments: load once, keep in registers across all l-tiles
    bf16x8 bq[3][3][4];
    {
        const int rowb = m0 + wm * 64 + r15;
        #pragma unroll
        for (int c = 0; c < 3; ++c)
            #pragma unroll
            for (int ks = 0; ks < 3; ++ks)
                #pragma unroll
                for (int fm = 0; fm < 4; ++fm) {
                    const int gp = ((ks * 4 + h) ^ r15) * 16;
                    bq[c][ks][fm] = *(const bf16x8*)(Bb + ((size_t)c * LL + rowb + fm * 16) * 256 + gp);
                }
    }

    const char* gAbase = Ab + w * 8192 + lane * 16;
    char* lA0 = Alds[0] + w * 8192;
    char* lA1 = Alds[1] + w * 8192;

    // prologue: stage (lt=0, c=0) into buf 0
    {
        const char* gA = gAbase + ((size_t)(sp * 10) * 128) * 256;
        #pragma unroll
        for (int i = 0; i < 8; ++i) gload_lds16(gA + i * 1024, lA0 + i * 1024);
    }

    int cur = 0;
    #pragma unroll 1
    for (int lt = 0; lt < 10; ++lt) {
        const int l0 = (sp * 10 + lt) * 128;
        f32x4 acc[4][4];
        #pragma unroll
        for (int i = 0; i < 4; ++i)
            #pragma unroll
            for (int j = 0; j < 4; ++j) acc[i][j] = fzero;

        #pragma unroll
        for (int c = 0; c < 3; ++c) {
            if (c < 2 || lt < 9) {
                const int c2  = (c + 1) % 3;
                const int l0n = (c == 2) ? l0 + 128 : l0;
                const char* gA = gAbase + ((size_t)c2 * LL + l0n) * 256;
                char* lA = (cur ^ 1) ? lA1 : lA0;
                #pragma unroll
                for (int i = 0; i < 8; ++i) gload_lds16(gA + i * 1024, lA + i * 1024);
                asm volatile("s_waitcnt vmcnt(8)" ::: "memory");
            } else {
                asm volatile("s_waitcnt vmcnt(0)" ::: "memory");
            }
            __builtin_amdgcn_s_barrier();
            asm volatile("" ::: "memory");
            const char* lAr = Alds[cur];
            #pragma unroll
            for (int ks = 0; ks < 3; ++ks) {
                const int gp = ((ks * 4 + h) ^ r15) * 16;
                bf16x8 af[4];
                #pragma unroll
                for (int f = 0; f < 4; ++f)
                    af[f] = *(const bf16x8*)(lAr + (wl * 64 + f * 16 + r15) * 256 + gp);
                #pragma unroll
                for (int fl = 0; fl < 4; ++fl)
                    #pragma unroll
                    for (int fm = 0; fm < 4; ++fm)
                        acc[fl][fm] = __builtin_amdgcn_mfma_f32_16x16x32_bf16(
                            af[fl], bq[c][ks][fm], acc[fl][fm], 0, 0, 0);
            }
            asm volatile("s_waitcnt lgkmcnt(0)" ::: "memory");
            __builtin_amdgcn_s_barrier();
            asm volatile("" ::: "memory");
            cur ^= 1;
        }

        const int Tbase = (sp * 10 + lt) * 16 + wl * 8;
        #pragma unroll
        for (int fl = 0; fl < 4; ++fl) {
            #pragma unroll
            for (int fm = 0; fm < 4; ++fm) {
                f32x4 a = acc[fl][fm];
                float v = fmaxf(fmaxf(a[0], a[1]), fmaxf(a[2], a[3]));
                v = fmaxf(v, __shfl_xor(v, 16, 64));
                if ((h & 1) == 0) {
                    const int m = m0 + wm * 64 + fm * 16 + r15;
                    tileMax8[((size_t)b * LL + m) * NT8 + Tbase + fl * 2 + (h >> 1)] = __float2half(v);
                }
            }
        }
    }
}

// ---------------- scanfix: wave-per-(b,m), coalesced unfold rescore ----------------
__global__ __launch_bounds__(256) void scanfix_kernel(const float* __restrict__ PANunf,
                                                      const float* __restrict__ HSIunf,
                                                      const float* __restrict__ invH,
                                                      const float* __restrict__ invP,
                                                      const __half* __restrict__ tileMax8,
                                                      float* __restrict__ Sv, int* __restrict__ Sa) {
    const int gw = blockIdx.x * 4 + (threadIdx.x >> 6);   // b*LL + m
    const int lane = threadIdx.x & 63;
    const int b = gw / LL;
    const __half* tm = tileMax8 + (size_t)gw * NT8;

    float tv[13];
    #pragma unroll
    for (int i = 0; i < 13; ++i) {
        int T = i * 64 + lane;
        tv[i] = (T < NT8) ? __half2float(tm[T]) : -3.0e38f;
    }
    float v1 = tv[0];
    #pragma unroll
    for (int i = 1; i < 13; ++i) v1 = fmaxf(v1, tv[i]);
    #pragma unroll
    for (int d = 1; d < 64; d <<= 1) v1 = fmaxf(v1, __shfl_xor(v1, d, 64));
    const float th = v1 - DELTA;

    const float ihm = invH[gw];
    const int lql = lane >> 3, kq = lane & 7;

    float hreg[36];
    {
        const float4* hv4 = (const float4*)(HSIunf + (size_t)gw * 288 + kq * 36);
        #pragma unroll
        for (int j = 0; j < 9; ++j) {
            float4 v = hv4[j];
            hreg[j * 4 + 0] = v.x; hreg[j * 4 + 1] = v.y;
            hreg[j * 4 + 2] = v.z; hreg[j * 4 + 3] = v.w;
        }
    }

    float bv = -3.0e38f; int bl = 0x7fffffff;

    #pragma unroll 1
    for (int i = 0; i < 13; ++i) {
        unsigned long long mask = __ballot(tv[i] >= th);
        while (mask) {
            const int t = __ffsll((long long)mask) - 1;
            mask &= mask - 1;
            const int T = i * 64 + t;
            const int l = T * 8 + lql;
            const float4* pv4 = (const float4*)(PANunf + ((size_t)b * LL + l) * 288 + kq * 36);
            float part = 0.f;
            #pragma unroll
            for (int jj = 0; jj < 9; ++jj) {
                float4 p = pv4[jj];
                part = fmaf(p.x, hreg[jj * 4 + 0], part);
                part = fmaf(p.y, hreg[jj * 4 + 1], part);
                part = fmaf(p.z, hreg[jj * 4 + 2], part);
                part = fmaf(p.w, hreg[jj * 4 + 3], part);
            }
            part += __shfl_xor(part, 1, 64);
            part += __shfl_xor(part, 2, 64);
            part += __shfl_xor(part, 4, 64);
            const float val = part * invP[b * LL + l] * ihm;
            if (val > bv || (val == bv && l < bl)) { bv = val; bl = l; }
        }
    }
    #pragma unroll
    for (int d = 1; d < 64; d <<= 1) {
        float ov = __shfl_xor(bv, d, 64);
        int   ol = __shfl_xor(bl, d, 64);
        if (ov > bv || (ov == bv && ol < bl)) { bv = ov; bl = ol; }
    }
    if (lane == 0) { Sv[gw] = bv; Sa[gw] = bl; }
}

// ---------------- T_lv3 = fold3x3(gathered PAN patches) / 9 ----------------
__global__ void tfold_kernel(const float* __restrict__ PAN, const int* __restrict__ Sa,
                             float* __restrict__ T) {
    int g = blockIdx.x * blockDim.x + threadIdx.x;
    if (g >= BB * CC * LL) return;
    int bc = g / LL, l = g - bc * LL;
    int b = bc >> 5;
    int y = div80(l), x = l - y * 80;
    const float* img = PAN + (size_t)bc * LL;
    const int* Sab = Sa + b * LL;
    float acc = 0.f;
    #pragma unroll
    for (int i = 0; i < 3; ++i) {
        int yp = y + 1 - i;
        if ((unsigned)yp >= 80u) continue;
        #pragma unroll
        for (int j = 0; j < 3; ++j) {
            int xp = x + 1 - j;
            if ((unsigned)xp >= 80u) continue;
            int a = Sab[yp * 80 + xp];
            int ya = div80(a), xa = a - ya * 80;
            int py = ya + i - 1, px = xa + j - 1;
            if ((unsigned)py < 80u && (unsigned)px < 80u) acc += img[py * 80 + px];
        }
    }
    T[g] = acc * (1.f / 9.f);
}

// ---------------- conv1: h = relu(conv3x3(concat(T,HSI), w1) + b1) ----------------
__global__ __launch_bounds__(256) void conv1_kernel(const float* __restrict__ T,
                                                    const float* __restrict__ HSI,
                                                    const float* __restrict__ w1,
                                                    const float* __restrict__ b1,
                                                    float* __restrict__ h) {
    __shared__ __align__(16) float wl[64][9][COG];   // 36.9 KB
    const int tid = threadIdx.x;
    const int co0 = blockIdx.y * COG;
    for (int idx = tid; idx < 64 * 9 * COG; idx += 256) {
        int cog = idx & (COG - 1);
        int rest = idx >> 4;
        int cin = rest / 9, tap = rest - cin * 9;
        wl[cin][tap][cog] = w1[(co0 + cog) * (64 * 9) + cin * 9 + tap];
    }
    __syncthreads();
    const int g = blockIdx.x * 256 + tid;
    const int b = g / LL, l = g - b * LL;
    const int y = div80(l), x = l - y * 80;
    float acc[COG];
    #pragma unroll
    for (int i = 0; i < COG; ++i) acc[i] = 0.f;
    for (int cin = 0; cin < 64; ++cin) {
        const float* img = (cin < CC) ? (T + (size_t)(b * CC + cin) * LL)
                                      : (HSI + (size_t)(b * CC + (cin - CC)) * LL);
        float tap[9];
        #pragma unroll
        for (int i = 0; i < 3; ++i)
            #pragma unroll
            for (int j = 0; j < 3; ++j) {
                int yy = y + i - 1, xx = x + j - 1;
                tap[i * 3 + j] = ((unsigned)yy < 80u && (unsigned)xx < 80u) ? img[yy * 80 + xx] : 0.f;
            }
        #pragma unroll
        for (int t9 = 0; t9 < 9; ++t9) {
            #pragma unroll
            for (int q4 = 0; q4 < COG / 4; ++q4) {
                const float4 wv = *reinterpret_cast<const float4*>(&wl[cin][t9][q4 * 4]);
                acc[q4 * 4 + 0] = fmaf(tap[t9], wv.x, acc[q4 * 4 + 0]);
                acc[q4 * 4 + 1] = fmaf(tap[t9], wv.y, acc[q4 * 4 + 1]);
                acc[q4 * 4 + 2] = fmaf(tap[t9], wv.z, acc[q4 * 4 + 2]);
                acc[q4 * 4 + 3] = fmaf(tap[t9], wv.w, acc[q4 * 4 + 3]);
            }
        }
    }
    #pragma unroll
    for (int cog = 0; cog < COG; ++cog) {
        float v = acc[cog] + b1[co0 + cog];
        h[(size_t)(b * CC + co0 + cog) * LL + l] = fmaxf(v, 0.f);
    }
}

// ---------------- conv2: out = (conv3x3(h, w2) + b2) * S + HSI ----------------
__global__ __launch_bounds__(256) void conv2_kernel(const float* __restrict__ hbuf,
                                                    const float* __restrict__ HSI,
                                                    const float* __restrict__ Sv,
                                                    const float* __restrict__ w2,
                                                    const float* __restrict__ b2,
                                                    float* __restrict__ out) {
    __shared__ __align__(16) float wl[CC][9][COG];   // 18.4 KB
    const int tid = threadIdx.x;
    const int co0 = blockIdx.y * COG;
    for (int idx = tid; idx < CC * 9 * COG; idx += 256) {
        int cog = idx & (COG - 1);
        int rest = idx >> 4;
        int cin = rest / 9, tap = rest - cin * 9;
        wl[cin][tap][cog] = w2[(co0 + cog) * (CC * 9) + cin * 9 + tap];
    }
    __syncthreads();
    const int g = blockIdx.x * 256 + tid;
    const int b = g / LL, l = g - b * LL;
    const int y = div80(l), x = l - y * 80;
    float acc[COG];
    #pragma unroll
    for (int i = 0; i < COG; ++i) acc[i] = 0.f;
    for (int cin = 0; cin < CC; ++cin) {
        const float* img = hbuf + (size_t)(b * CC + cin) * LL;
        float tap[9];
        #pragma unroll
        for (int i = 0; i < 3; ++i)
            #pragma unroll
            for (int j = 0; j < 3; ++j) {
                int yy = y + i - 1, xx = x + j - 1;
                tap[i * 3 + j] = ((unsigned)yy < 80u && (unsigned)xx < 80u) ? img[yy * 80 + xx] : 0.f;
            }
        #pragma unroll
        for (int t9 = 0; t9 < 9; ++t9) {
            #pragma unroll
            for (int q4 = 0; q4 < COG / 4; ++q4) {
                const float4 wv = *reinterpret_cast<const float4*>(&wl[cin][t9][q4 * 4]);
                acc[q4 * 4 + 0] = fmaf(tap[t9], wv.x, acc[q4 * 4 + 0]);
                acc[q4 * 4 + 1] = fmaf(tap[t9], wv.y, acc[q4 * 4 + 1]);
                acc[q4 * 4 + 2] = fmaf(tap[t9], wv.z, acc[q4 * 4 + 2]);
                acc[q4 * 4 + 3] = fmaf(tap[t9], wv.w, acc[q4 * 4 + 3]);
            }
        }
    }
    const float s = Sv[b * LL + l];
    #pragma unroll
    for (int cog = 0; cog < COG; ++cog) {
        int c = co0 + cog;
        out[(size_t)(b * CC + c) * LL + l] = fmaf(acc[cog] + b2[c], s, HSI[(size_t)(b * CC + c) * LL + l]);
    }
}

extern "C" void kernel_launch(void* const* d_in, const int* in_sizes, int n_in,
                              void* d_out, int out_size, void* d_ws, size_t ws_size,
                              hipStream_t stream) {
    const float* HSI = (const float*)d_in[0];
    const float* PAN = (const float*)d_in[1];
    const float* w1  = (const float*)d_in[2];
    const float* b1  = (const float*)d_in[3];
    const float* w2  = (const float*)d_in[4];
    const float* b2  = (const float*)d_in[5];
    float* out = (float*)d_out;

    char* ws = (char*)d_ws;
    size_t off = 0;
    auto alloc = [&](size_t bytes) -> void* {
        void* p = ws + off;
        off += (bytes + 255) & ~(size_t)255;
        return p;
    };
    float* invH  = (float*)alloc((size_t)BB * LL * 4);
    float* invP  = (float*)alloc((size_t)BB * LL * 4);
    char*  Apack = (char*) alloc((size_t)BB * 3 * LL * 256);   // 9.83 MB
    char*  Bpack = (char*) alloc((size_t)BB * 3 * LL * 256);   // 9.83 MB
    __half* tileMax8 = (__half*)alloc((size_t)BB * LL * NT8 * 2);    // 20.5 MB
    float* PANunf = (float*)alloc((size_t)BB * LL * 288 * 4);  // 14.75 MB
    float* HSIunf = (float*)alloc((size_t)BB * LL * 288 * 4);  // 14.75 MB
    float* Sv    = (float*)alloc((size_t)BB * LL * 4);
    int*   Sa    = (int*)  alloc((size_t)BB * LL * 4);
    float* T     = (float*)alloc((size_t)BB * CC * LL * 4);
    float* hbuf  = (float*)alloc((size_t)BB * CC * LL * 4);

    fusedunf_kernel<<<dim3(80, 2, BB), 256, 0, stream>>>(HSI, PAN, invH, invP,
                                                         PANunf, HSIunf, Apack, Bpack);
    simq_kernel<<<dim3(500), 256, 0, stream>>>(Apack, Bpack, tileMax8);
    scanfix_kernel<<<dim3(BB * LL / 4), 256, 0, stream>>>(PANunf, HSIunf, invH, invP, tileMax8, Sv, Sa);
    tfold_kernel<<<dim3((BB * CC * LL + 255) / 256), 256, 0, stream>>>(PAN, Sa, T);
    conv1_kernel<<<dim3(BB * LL / 256, CC / COG), 256, 0, stream>>>(T, HSI, w1, b1, hbuf);
    conv2_kernel<<<dim3(BB * LL / 256, CC / COG), 256, 0, stream>>>(hbuf, HSI, Sv, w2, b2, out);
}